// Round 1
// baseline (4108.506 us; speedup 1.0000x reference)
//
#include <hip/hip_runtime.h>
#include <math.h>

#define MIN_D (-3.402823466e+38f)

constexpr int Bb = 2, Ss = 2048, Dm = 1024, Hh = 16, HDd = 64, NV = 8192, DRr = 128;
constexpr int Mrows = Bb * Ss;   // 4096

// ---------------------------------------------------------------------------
// Generic f32 GEMM:  C[M,N] = A[M,K] @ W[K,N] + bias[N]
// 64x64 tile, 256 threads, 4x4 per thread, BK=16.
// ---------------------------------------------------------------------------
__global__ __launch_bounds__(256)
void gemm_bias_f32(const float* __restrict__ A, const float* __restrict__ W,
                   const float* __restrict__ bias, float* __restrict__ C,
                   int N, int K)
{
    __shared__ float As[64][20];   // stride 20 floats = 80B (16B aligned, no pow2 bank hit)
    __shared__ float Ws[16][64];
    const int tid = threadIdx.x;
    const int row0 = blockIdx.y * 64, col0 = blockIdx.x * 64;
    const int tr = tid >> 4, tc = tid & 15;
    float acc[4][4] = {};

    for (int k0 = 0; k0 < K; k0 += 16) {
        {   // A tile 64x16
            int r = tid >> 2, c4 = (tid & 3) << 2;
            float4 av = *(const float4*)(A + (size_t)(row0 + r) * K + k0 + c4);
            *(float4*)&As[r][c4] = av;
        }
        {   // W tile 16x64
            int r = tid >> 4, c4 = (tid & 15) << 2;
            float4 wv = *(const float4*)(W + (size_t)(k0 + r) * N + col0 + c4);
            *(float4*)&Ws[r][c4] = wv;
        }
        __syncthreads();
#pragma unroll
        for (int kk = 0; kk < 16; ++kk) {
            float a[4];
#pragma unroll
            for (int i = 0; i < 4; ++i) a[i] = As[tr * 4 + i][kk];
            float4 bv = *(const float4*)&Ws[kk][tc * 4];
            float b[4] = {bv.x, bv.y, bv.z, bv.w};
#pragma unroll
            for (int i = 0; i < 4; ++i)
#pragma unroll
                for (int j = 0; j < 4; ++j)
                    acc[i][j] = fmaf(a[i], b[j], acc[i][j]);
        }
        __syncthreads();
    }
#pragma unroll
    for (int i = 0; i < 4; ++i) {
        int r = row0 + tr * 4 + i;
        int c = col0 + tc * 4;
        float4 ov;
        ov.x = acc[i][0] + bias[c + 0];
        ov.y = acc[i][1] + bias[c + 1];
        ov.z = acc[i][2] + bias[c + 2];
        ov.w = acc[i][3] + bias[c + 3];
        *(float4*)(C + (size_t)r * N + c) = ov;
    }
}

// ---------------------------------------------------------------------------
// Retrieval: per row (b,s), partial argmax of vq . v_keys[n] over an n-chunk
// of 1024. Grid (8 chunks, 64 row-tiles). Exact first-max tie-break.
// ---------------------------------------------------------------------------
__global__ __launch_bounds__(256)
void retrieve_argmax_partial(const float* __restrict__ vq,
                             const float* __restrict__ vkeys,
                             float* __restrict__ pmax, int* __restrict__ pidx)
{
    __shared__ float Qs[64][132];   // 132*4B = 528B rows: 16B aligned, banks spread
    __shared__ float Kt[128][68];   // [k][n] transposed keys, 272B rows
    const int tid = threadIdx.x;
    const int chunk = blockIdx.x;       // 0..7
    const int row0 = blockIdx.y * 64;   // row tile
    const int tr = tid >> 4, tc = tid & 15;

    {   // stage vq rows [64][128]
        int r = tid >> 2, cb = (tid & 3) * 32;
#pragma unroll
        for (int l = 0; l < 8; ++l) {
            float4 v = *(const float4*)(vq + (size_t)(row0 + r) * DRr + cb + l * 4);
            *(float4*)&Qs[r][cb + l * 4] = v;
        }
    }

    float vmax[4];
    int   vidx[4];
#pragma unroll
    for (int i = 0; i < 4; ++i) { vmax[i] = -INFINITY; vidx[i] = 0; }

    for (int nt = 0; nt < 16; ++nt) {
        const int n0 = chunk * 1024 + nt * 64;
        __syncthreads();
        {   // stage keys transposed: Kt[k][n]
            int n = tid >> 2, kb = (tid & 3) * 32;
#pragma unroll
            for (int l = 0; l < 8; ++l) {
                float4 v = *(const float4*)(vkeys + (size_t)(n0 + n) * DRr + kb + l * 4);
                Kt[kb + l * 4 + 0][n] = v.x;
                Kt[kb + l * 4 + 1][n] = v.y;
                Kt[kb + l * 4 + 2][n] = v.z;
                Kt[kb + l * 4 + 3][n] = v.w;
            }
        }
        __syncthreads();

        float acc[4][4] = {};
#pragma unroll 8
        for (int kk = 0; kk < 128; ++kk) {
            float a[4];
#pragma unroll
            for (int i = 0; i < 4; ++i) a[i] = Qs[tr * 4 + i][kk];
            float4 bv = *(const float4*)&Kt[kk][tc * 4];
            float b[4] = {bv.x, bv.y, bv.z, bv.w};
#pragma unroll
            for (int i = 0; i < 4; ++i)
#pragma unroll
                for (int j = 0; j < 4; ++j)
                    acc[i][j] = fmaf(a[i], b[j], acc[i][j]);
        }
#pragma unroll
        for (int i = 0; i < 4; ++i)
#pragma unroll
            for (int j = 0; j < 4; ++j) {
                int n = n0 + tc * 4 + j;
                if (acc[i][j] > vmax[i]) { vmax[i] = acc[i][j]; vidx[i] = n; }
            }
    }

    // reduce across the 16 lanes sharing this row group (first-max tie-break)
#pragma unroll
    for (int off = 1; off < 16; off <<= 1) {
#pragma unroll
        for (int i = 0; i < 4; ++i) {
            float om = __shfl_xor(vmax[i], off);
            int   oi = __shfl_xor(vidx[i], off);
            if (om > vmax[i] || (om == vmax[i] && oi < vidx[i])) { vmax[i] = om; vidx[i] = oi; }
        }
    }
    if (tc == 0) {
#pragma unroll
        for (int i = 0; i < 4; ++i) {
            int r = row0 + tr * 4 + i;
            pmax[r * 8 + chunk] = vmax[i];
            pidx[r * 8 + chunk] = vidx[i];
        }
    }
}

__global__ void argmax_combine(const float* __restrict__ pmax,
                               const int* __restrict__ pidx,
                               int* __restrict__ idx)
{
    int r = blockIdx.x * blockDim.x + threadIdx.x;
    if (r >= Mrows) return;
    float best = pmax[r * 8];
    int   bi   = pidx[r * 8];
#pragma unroll
    for (int c = 1; c < 8; ++c) {
        float m2 = pmax[r * 8 + c];
        int   i2 = pidx[r * 8 + c];
        if (m2 > best || (m2 == best && i2 < bi)) { best = m2; bi = i2; }
    }
    idx[r] = bi;
}

__global__ __launch_bounds__(256)
void build_v(const float* __restrict__ hs, const float* __restrict__ vembed,
             const int* __restrict__ idx, float* __restrict__ v)
{
    int row = blockIdx.x;
    int id = idx[row];
    int c = threadIdx.x * 4;
    float4 a = *(const float4*)(hs + (size_t)row * Dm + c);
    float4 e = *(const float4*)(vembed + (size_t)id * Dm + c);
    float4 r;
    r.x = a.x * e.x; r.y = a.y * e.y; r.z = a.z * e.z; r.w = a.w * e.w;
    *(float4*)(v + (size_t)row * Dm + c) = r;
}

// ---------------------------------------------------------------------------
// Flash-style f32 attention with reference-exact additive -FLT_MAX masking.
// Block = (qtile 64 rows, h, b); 256 threads = 16(rowgrp) x 16(colgrp), 4x4 each.
// Full key range is processed (NOT causally skipped) so that fully-masked rows
// reproduce the reference's uniform softmax over all 2048 keys.
// ---------------------------------------------------------------------------
__global__ __launch_bounds__(256)
void attn_f32(const float* __restrict__ q, const float* __restrict__ k,
              const float* __restrict__ v, const float* __restrict__ am,
              const float* __restrict__ dm, float* __restrict__ o)
{
    __shared__ float Qs[64][68];
    __shared__ float Kt[64][68];     // [hd][key] transposed
    __shared__ float Vs[64][68];     // [key][hd]
    __shared__ float Ps[64][68];     // probs, per-wave private rows
    __shared__ float amdm[Ss];
    const int tid = threadIdx.x;
    const int qt = blockIdx.x, h = blockIdx.y, b = blockIdx.z;
    const int row0 = qt * 64;
    const int tr = tid >> 4, tc = tid & 15;

    {   // stage Q tile (rows row0.., cols h*64..)
        int r = tid >> 2, cb = (tid & 3) * 16;
#pragma unroll
        for (int l = 0; l < 4; ++l) {
            float4 t = *(const float4*)(q + ((size_t)(b * Ss + row0 + r)) * Dm + h * HDd + cb + l * 4);
            *(float4*)&Qs[r][cb + l * 4] = t;
        }
    }
    for (int j = tid; j < Ss; j += 256)
        amdm[j] = am[b * Ss + j] * dm[h * Ss + j];

    float mrun[4], lrun[4], acc[4][4] = {};
#pragma unroll
    for (int i = 0; i < 4; ++i) { mrun[i] = -INFINITY; lrun[i] = 0.f; }

    for (int kt = 0; kt < Ss / 64; ++kt) {
        __syncthreads();   // previous tile's PV reads done before restage
        {
            int n = tid >> 2, cb = (tid & 3) * 16;
            size_t base = ((size_t)(b * Ss + kt * 64 + n)) * Dm + h * HDd;
#pragma unroll
            for (int l2 = 0; l2 < 4; ++l2) {
                float4 tk = *(const float4*)(k + base + cb + l2 * 4);
                Kt[cb + l2 * 4 + 0][n] = tk.x;
                Kt[cb + l2 * 4 + 1][n] = tk.y;
                Kt[cb + l2 * 4 + 2][n] = tk.z;
                Kt[cb + l2 * 4 + 3][n] = tk.w;
                float4 tv = *(const float4*)(v + base + cb + l2 * 4);
                *(float4*)&Vs[n][cb + l2 * 4] = tv;
            }
        }
        __syncthreads();

        // S = Q K^T
        float s[4][4] = {};
#pragma unroll
        for (int kk = 0; kk < 64; ++kk) {
            float a[4];
#pragma unroll
            for (int i = 0; i < 4; ++i) a[i] = Qs[tr * 4 + i][kk];
            float4 bv = *(const float4*)&Kt[kk][tc * 4];
            float bb[4] = {bv.x, bv.y, bv.z, bv.w};
#pragma unroll
            for (int i = 0; i < 4; ++i)
#pragma unroll
                for (int j = 0; j < 4; ++j)
                    s[i][j] = fmaf(a[i], bb[j], s[i][j]);
        }
        // scale + additive mask (reference semantics: score/8 + {0 | -FLT_MAX})
#pragma unroll
        for (int i = 0; i < 4; ++i) {
            int ig = row0 + tr * 4 + i;
#pragma unroll
            for (int j = 0; j < 4; ++j) {
                int col = kt * 64 + tc * 4 + j;
                float mv = (col > ig || amdm[col] == 0.f) ? MIN_D : 0.f;
                s[i][j] = s[i][j] * 0.125f + mv;
            }
        }
        // online softmax (row stats shuffled across the 16 lanes of a row group)
#pragma unroll
        for (int i = 0; i < 4; ++i) {
            float pm = fmaxf(fmaxf(s[i][0], s[i][1]), fmaxf(s[i][2], s[i][3]));
#pragma unroll
            for (int off = 1; off < 16; off <<= 1)
                pm = fmaxf(pm, __shfl_xor(pm, off));
            float mn = fmaxf(mrun[i], pm);
            float sc = expf(mrun[i] - mn);       // -inf - finite -> 0 on first tile
            float p[4], rs = 0.f;
#pragma unroll
            for (int j = 0; j < 4; ++j) { p[j] = expf(s[i][j] - mn); rs += p[j]; }
#pragma unroll
            for (int off = 1; off < 16; off <<= 1)
                rs += __shfl_xor(rs, off);
            lrun[i] = lrun[i] * sc + rs;
            mrun[i] = mn;
#pragma unroll
            for (int j = 0; j < 4; ++j) acc[i][j] *= sc;
            float4 pv = {p[0], p[1], p[2], p[3]};
            *(float4*)&Ps[tr * 4 + i][tc * 4] = pv;
        }
        // PV: rows of Ps are written and read by the same wave (in-order LDS)
#pragma unroll 4
        for (int n = 0; n < 64; ++n) {
            float4 bv = *(const float4*)&Vs[n][tc * 4];
            float bb[4] = {bv.x, bv.y, bv.z, bv.w};
            float a[4];
#pragma unroll
            for (int i = 0; i < 4; ++i) a[i] = Ps[tr * 4 + i][n];
#pragma unroll
            for (int i = 0; i < 4; ++i)
#pragma unroll
                for (int j = 0; j < 4; ++j)
                    acc[i][j] = fmaf(a[i], bb[j], acc[i][j]);
        }
    }

#pragma unroll
    for (int i = 0; i < 4; ++i) {
        int ig = row0 + tr * 4 + i;
        float inv = 1.0f / lrun[i];
        float4 ov;
        ov.x = acc[i][0] * inv; ov.y = acc[i][1] * inv;
        ov.z = acc[i][2] * inv; ov.w = acc[i][3] * inv;
        *(float4*)(o + ((size_t)(b * Ss + ig)) * Dm + h * HDd + tc * 4) = ov;
    }
}

// ---------------------------------------------------------------------------
extern "C" void kernel_launch(void* const* d_in, const int* in_sizes, int n_in,
                              void* d_out, int out_size, void* d_ws, size_t ws_size,
                              hipStream_t stream)
{
    const float* hs     = (const float*)d_in[0];
    const float* amask  = (const float*)d_in[1];
    const float* Wq     = (const float*)d_in[2];
    const float* bq     = (const float*)d_in[3];
    const float* Wk     = (const float*)d_in[4];
    const float* bk     = (const float*)d_in[5];
    const float* dmask  = (const float*)d_in[6];
    const float* Wvq    = (const float*)d_in[7];
    const float* bvq    = (const float*)d_in[8];
    const float* vkeys  = (const float*)d_in[9];
    const float* vembed = (const float*)d_in[10];
    const float* Wo     = (const float*)d_in[11];
    const float* bo     = (const float*)d_in[12];
    float* out = (float*)d_out;

    char* w = (char*)d_ws;
    size_t off = 0;
    auto take = [&](size_t n) { char* p = w + off; off = (off + n + 255) & ~(size_t)255; return p; };
    float* qb    = (float*)take((size_t)Mrows * Dm * 4);
    float* kb    = (float*)take((size_t)Mrows * Dm * 4);
    float* vqb   = (float*)take((size_t)Mrows * DRr * 4);
    float* vbuf  = (float*)take((size_t)Mrows * Dm * 4);
    float* attno = (float*)take((size_t)Mrows * Dm * 4);
    float* pmax  = (float*)take((size_t)Mrows * 8 * 4);
    int*   pidx  = (int*)take((size_t)Mrows * 8 * 4);
    int*   idxb  = (int*)take((size_t)Mrows * 4);

    dim3 blk(256);
    // projections
    gemm_bias_f32<<<dim3(Dm / 64, Mrows / 64), blk, 0, stream>>>(hs, Wq, bq, qb, Dm, Dm);
    gemm_bias_f32<<<dim3(Dm / 64, Mrows / 64), blk, 0, stream>>>(hs, Wk, bk, kb, Dm, Dm);
    gemm_bias_f32<<<dim3(DRr / 64, Mrows / 64), blk, 0, stream>>>(hs, Wvq, bvq, vqb, DRr, Dm);
    // top-1 retrieval (f32 exact for argmax stability)
    retrieve_argmax_partial<<<dim3(8, Mrows / 64), blk, 0, stream>>>(vqb, vkeys, pmax, pidx);
    argmax_combine<<<dim3((Mrows + 255) / 256), blk, 0, stream>>>(pmax, pidx, idxb);
    build_v<<<dim3(Mrows), blk, 0, stream>>>(hs, vembed, idxb, vbuf);
    // attention
    attn_f32<<<dim3(Ss / 64, Hh, Bb), blk, 0, stream>>>(qb, kb, vbuf, amask, dmask, attno);
    // output projection
    gemm_bias_f32<<<dim3(Dm / 64, Mrows / 64), blk, 0, stream>>>(attno, Wo, bo, out, Dm, Dm);
}

// Round 2
// 833.105 us; speedup vs baseline: 4.9316x; 4.9316x over previous
//
#include <hip/hip_runtime.h>
#include <math.h>

#define MIN_D (-3.402823466e+38f)

constexpr int Bb = 2, Ss = 2048, Dm = 1024, Hh = 16, HDd = 64, NV = 8192, DRr = 128;
constexpr int Mrows = Bb * Ss;   // 4096

typedef __attribute__((ext_vector_type(8))) short bf16x8;
typedef __attribute__((ext_vector_type(4))) float f32x4;

__device__ inline unsigned short f2bf(float x) {
    union { float f; unsigned u; } v; v.f = x;
    unsigned r = v.u + 0x7fff + ((v.u >> 16) & 1);   // RNE
    return (unsigned short)(r >> 16);
}

// ---------------------------------------------------------------------------
// Generic f32 GEMM:  C[M,N] = A[M,K] @ W[K,N] + bias[N]   (unchanged from R1)
// ---------------------------------------------------------------------------
__global__ __launch_bounds__(256)
void gemm_bias_f32(const float* __restrict__ A, const float* __restrict__ W,
                   const float* __restrict__ bias, float* __restrict__ C,
                   int N, int K)
{
    __shared__ float As[64][20];
    __shared__ float Ws[16][64];
    const int tid = threadIdx.x;
    const int row0 = blockIdx.y * 64, col0 = blockIdx.x * 64;
    const int tr = tid >> 4, tc = tid & 15;
    float acc[4][4] = {};

    for (int k0 = 0; k0 < K; k0 += 16) {
        {
            int r = tid >> 2, c4 = (tid & 3) << 2;
            float4 av = *(const float4*)(A + (size_t)(row0 + r) * K + k0 + c4);
            *(float4*)&As[r][c4] = av;
        }
        {
            int r = tid >> 4, c4 = (tid & 15) << 2;
            float4 wv = *(const float4*)(W + (size_t)(k0 + r) * N + col0 + c4);
            *(float4*)&Ws[r][c4] = wv;
        }
        __syncthreads();
#pragma unroll
        for (int kk = 0; kk < 16; ++kk) {
            float a[4];
#pragma unroll
            for (int i = 0; i < 4; ++i) a[i] = As[tr * 4 + i][kk];
            float4 bv = *(const float4*)&Ws[kk][tc * 4];
            float b[4] = {bv.x, bv.y, bv.z, bv.w};
#pragma unroll
            for (int i = 0; i < 4; ++i)
#pragma unroll
                for (int j = 0; j < 4; ++j)
                    acc[i][j] = fmaf(a[i], b[j], acc[i][j]);
        }
        __syncthreads();
    }
#pragma unroll
    for (int i = 0; i < 4; ++i) {
        int r = row0 + tr * 4 + i;
        int c = col0 + tc * 4;
        float4 ov;
        ov.x = acc[i][0] + bias[c + 0];
        ov.y = acc[i][1] + bias[c + 1];
        ov.z = acc[i][2] + bias[c + 2];
        ov.w = acc[i][3] + bias[c + 3];
        *(float4*)(C + (size_t)r * N + c) = ov;
    }
}

// ---------------------------------------------------------------------------
// Retrieval (f32 exact — argmax stability). Unchanged from R1.
// ---------------------------------------------------------------------------
__global__ __launch_bounds__(256)
void retrieve_argmax_partial(const float* __restrict__ vq,
                             const float* __restrict__ vkeys,
                             float* __restrict__ pmax, int* __restrict__ pidx)
{
    __shared__ float Qs[64][132];
    __shared__ float Kt[128][68];
    const int tid = threadIdx.x;
    const int chunk = blockIdx.x;
    const int row0 = blockIdx.y * 64;
    const int tr = tid >> 4, tc = tid & 15;

    {
        int r = tid >> 2, cb = (tid & 3) * 32;
#pragma unroll
        for (int l = 0; l < 8; ++l) {
            float4 v = *(const float4*)(vq + (size_t)(row0 + r) * DRr + cb + l * 4);
            *(float4*)&Qs[r][cb + l * 4] = v;
        }
    }

    float vmax[4];
    int   vidx[4];
#pragma unroll
    for (int i = 0; i < 4; ++i) { vmax[i] = -INFINITY; vidx[i] = 0; }

    for (int nt = 0; nt < 16; ++nt) {
        const int n0 = chunk * 1024 + nt * 64;
        __syncthreads();
        {
            int n = tid >> 2, kb = (tid & 3) * 32;
#pragma unroll
            for (int l = 0; l < 8; ++l) {
                float4 v = *(const float4*)(vkeys + (size_t)(n0 + n) * DRr + kb + l * 4);
                Kt[kb + l * 4 + 0][n] = v.x;
                Kt[kb + l * 4 + 1][n] = v.y;
                Kt[kb + l * 4 + 2][n] = v.z;
                Kt[kb + l * 4 + 3][n] = v.w;
            }
        }
        __syncthreads();

        float acc[4][4] = {};
#pragma unroll 8
        for (int kk = 0; kk < 128; ++kk) {
            float a[4];
#pragma unroll
            for (int i = 0; i < 4; ++i) a[i] = Qs[tr * 4 + i][kk];
            float4 bv = *(const float4*)&Kt[kk][tc * 4];
            float b[4] = {bv.x, bv.y, bv.z, bv.w};
#pragma unroll
            for (int i = 0; i < 4; ++i)
#pragma unroll
                for (int j = 0; j < 4; ++j)
                    acc[i][j] = fmaf(a[i], b[j], acc[i][j]);
        }
#pragma unroll
        for (int i = 0; i < 4; ++i)
#pragma unroll
            for (int j = 0; j < 4; ++j) {
                int n = n0 + tc * 4 + j;
                if (acc[i][j] > vmax[i]) { vmax[i] = acc[i][j]; vidx[i] = n; }
            }
    }

#pragma unroll
    for (int off = 1; off < 16; off <<= 1) {
#pragma unroll
        for (int i = 0; i < 4; ++i) {
            float om = __shfl_xor(vmax[i], off);
            int   oi = __shfl_xor(vidx[i], off);
            if (om > vmax[i] || (om == vmax[i] && oi < vidx[i])) { vmax[i] = om; vidx[i] = oi; }
        }
    }
    if (tc == 0) {
#pragma unroll
        for (int i = 0; i < 4; ++i) {
            int r = row0 + tr * 4 + i;
            pmax[r * 8 + chunk] = vmax[i];
            pidx[r * 8 + chunk] = vidx[i];
        }
    }
}

__global__ void argmax_combine(const float* __restrict__ pmax,
                               const int* __restrict__ pidx,
                               int* __restrict__ idx)
{
    int r = blockIdx.x * blockDim.x + threadIdx.x;
    if (r >= Mrows) return;
    float best = pmax[r * 8];
    int   bi   = pidx[r * 8];
#pragma unroll
    for (int c = 1; c < 8; ++c) {
        float m2 = pmax[r * 8 + c];
        int   i2 = pidx[r * 8 + c];
        if (m2 > best || (m2 == best && i2 < bi)) { best = m2; bi = i2; }
    }
    idx[r] = bi;
}

__global__ __launch_bounds__(256)
void build_v(const float* __restrict__ hs, const float* __restrict__ vembed,
             const int* __restrict__ idx, float* __restrict__ v)
{
    int row = blockIdx.x;
    int id = idx[row];
    int c = threadIdx.x * 4;
    float4 a = *(const float4*)(hs + (size_t)row * Dm + c);
    float4 e = *(const float4*)(vembed + (size_t)id * Dm + c);
    float4 r;
    r.x = a.x * e.x; r.y = a.y * e.y; r.z = a.z * e.z; r.w = a.w * e.w;
    *(float4*)(v + (size_t)row * Dm + c) = r;
}

// ---------------------------------------------------------------------------
// mean of v over sequence per batch: meanv[b][d] = (1/2048) sum_s v[b][s][d]
// Needed for fully-masked rows (reference = uniform softmax over ALL keys).
// ---------------------------------------------------------------------------
__global__ __launch_bounds__(256)
void mean_v_kernel(const float* __restrict__ v, float* __restrict__ mv)
{
    __shared__ float part[4][64];
    const int d0 = blockIdx.x * 64;
    const int b  = blockIdx.y;
    const int dl = threadIdx.x & 63, jc = threadIdx.x >> 6;
    float s = 0.f;
#pragma unroll 4
    for (int j = jc * 512; j < jc * 512 + 512; ++j)
        s += v[((size_t)(b * Ss + j)) * Dm + d0 + dl];
    part[jc][dl] = s;
    __syncthreads();
    if (threadIdx.x < 64) {
        float t = part[0][dl] + part[1][dl] + part[2][dl] + part[3][dl];
        mv[b * Dm + d0 + dl] = t * (1.f / 2048.f);
    }
}

// ---------------------------------------------------------------------------
// bf16 MFMA flash attention.
// Block: 256 thr = 4 waves; wave w owns q rows [qt*64 + w*16, +16).
// K tile [64 key][64 d] bf16 in LDS, XOR-swizzled (byte ^= (key&7)<<4).
// V tile stored transposed [64 d][72 key] bf16 (144B rows, 16B aligned).
// P routed wave-privately through swizzled LDS [64 q][64 key] bf16.
// Causal tile skip kt<=qt; fully-masked rows (mrun==MIN_D) -> meanv override.
// MFMA conventions (m89-verified): D: row q=(l>>4)*4+reg, col=l&15.
// A frag: row=l&15, k=8*(l>>4)+i.  B frag: col=l&15, k=8*(l>>4)+i.
// (Any HW k-permutation cancels since A and B use the same convention.)
// ---------------------------------------------------------------------------
__global__ __launch_bounds__(256)
void attn_mfma(const float* __restrict__ q, const float* __restrict__ k,
               const float* __restrict__ v, const float* __restrict__ am,
               const float* __restrict__ dm, const float* __restrict__ meanv,
               float* __restrict__ o)
{
    __shared__ __align__(16) unsigned char Ksm[64 * 128];   // swizzled bf16 [key][d]
    __shared__ __align__(16) unsigned short Vsm[64 * 72];   // bf16 [d][key], pad 72
    __shared__ __align__(16) unsigned char Psm[64 * 128];   // swizzled bf16 [q][key]
    __shared__ float amdm[Ss];                               // 0 or MIN_D

    const int tid = threadIdx.x;
    const int l = tid & 63, w = tid >> 6;
    const int l15 = l & 15, l4 = l >> 4;
    const int qt = gridDim.x - 1 - blockIdx.x;   // heavy tiles first
    const int h = blockIdx.y, b = blockIdx.z;
    const int row0 = qt * 64;

    for (int j = tid; j < Ss; j += 256)
        amdm[j] = (am[b * Ss + j] * dm[h * Ss + j] == 0.f) ? MIN_D : 0.f;

    // Q fragments in registers (row = l&15 of this wave's 16 q rows)
    bf16x8 qf[2];
    {
        const float* qp = q + ((size_t)(b * Ss + row0 + w * 16 + l15)) * Dm
                          + h * HDd + l4 * 8;
#pragma unroll
        for (int half = 0; half < 2; ++half) {
            float4 x = *(const float4*)(qp + half * 32);
            float4 y = *(const float4*)(qp + half * 32 + 4);
            bf16x8 t;
            t[0] = (short)f2bf(x.x); t[1] = (short)f2bf(x.y);
            t[2] = (short)f2bf(x.z); t[3] = (short)f2bf(x.w);
            t[4] = (short)f2bf(y.x); t[5] = (short)f2bf(y.y);
            t[6] = (short)f2bf(y.z); t[7] = (short)f2bf(y.w);
            qf[half] = t;
        }
    }

    f32x4 acc[4];                       // [dblk]; reg -> q row
#pragma unroll
    for (int d2 = 0; d2 < 4; ++d2) acc[d2] = (f32x4)(0.f);
    float mrun[4], lrun[4];
#pragma unroll
    for (int r = 0; r < 4; ++r) { mrun[r] = -INFINITY; lrun[r] = 0.f; }

    for (int kt = 0; kt <= qt; ++kt) {
        __syncthreads();   // prev tile consumed (also covers amdm on kt=0)
        {   // stage K (swizzled) and V (transposed): thread -> row r, 16 d's
            const int r = tid >> 2, cb = (tid & 3) << 4;
            const size_t gbase = ((size_t)(b * Ss + kt * 64 + r)) * Dm + h * HDd + cb;
            unsigned ku[8];
            unsigned short vb16[16];
#pragma unroll
            for (int t4 = 0; t4 < 4; ++t4) {
                float4 kx = *(const float4*)(k + gbase + t4 * 4);
                float4 vx = *(const float4*)(v + gbase + t4 * 4);
                ku[t4 * 2 + 0] = (unsigned)f2bf(kx.x) | ((unsigned)f2bf(kx.y) << 16);
                ku[t4 * 2 + 1] = (unsigned)f2bf(kx.z) | ((unsigned)f2bf(kx.w) << 16);
                vb16[t4 * 4 + 0] = f2bf(vx.x); vb16[t4 * 4 + 1] = f2bf(vx.y);
                vb16[t4 * 4 + 2] = f2bf(vx.z); vb16[t4 * 4 + 3] = f2bf(vx.w);
            }
            const unsigned swz = (r & 7) << 4;
            uint4 a0; a0.x = ku[0]; a0.y = ku[1]; a0.z = ku[2]; a0.w = ku[3];
            uint4 a1; a1.x = ku[4]; a1.y = ku[5]; a1.z = ku[6]; a1.w = ku[7];
            *(uint4*)&Ksm[r * 128 + ((cb * 2) ^ swz)]      = a0;
            *(uint4*)&Ksm[r * 128 + ((cb * 2 + 16) ^ swz)] = a1;
#pragma unroll
            for (int j = 0; j < 16; ++j) Vsm[(cb + j) * 72 + r] = vb16[j];
        }
        __syncthreads();

        // S = Q K^T  (4 key sub-tiles of 16)
        f32x4 sreg[4];
#pragma unroll
        for (int kb = 0; kb < 4; ++kb) {
            const int key = kb * 16 + l15;
            const unsigned swz = (key & 7) << 4;
            bf16x8 k0 = *(bf16x8*)&Ksm[key * 128 + ((l4 * 16) ^ swz)];
            bf16x8 k1 = *(bf16x8*)&Ksm[key * 128 + ((64 + l4 * 16) ^ swz)];
            f32x4 s = (f32x4)(0.f);
            s = __builtin_amdgcn_mfma_f32_16x16x32_bf16(qf[0], k0, s, 0, 0, 0);
            s = __builtin_amdgcn_mfma_f32_16x16x32_bf16(qf[1], k1, s, 0, 0, 0);
            sreg[kb] = s;
        }

        // mask + online softmax + P store (bf16, swizzled, wave-private rows)
#pragma unroll
        for (int r = 0; r < 4; ++r) {
            const int qrow = row0 + w * 16 + l4 * 4 + r;
            float sv[4];
#pragma unroll
            for (int kb = 0; kb < 4; ++kb) {
                const int col = kt * 64 + kb * 16 + l15;
                const float mv = (col > qrow) ? MIN_D : amdm[col];
                sv[kb] = sreg[kb][r] * 0.125f + mv;
            }
            float pm = fmaxf(fmaxf(sv[0], sv[1]), fmaxf(sv[2], sv[3]));
#pragma unroll
            for (int off = 1; off < 16; off <<= 1) pm = fmaxf(pm, __shfl_xor(pm, off));
            const float mn = fmaxf(mrun[r], pm);
            const float sc = expf(mrun[r] - mn);   // -inf - finite -> 0
            float rs = 0.f;
            unsigned short pb[4];
#pragma unroll
            for (int kb = 0; kb < 4; ++kb) {
                float p = expf(sv[kb] - mn);
                rs += p;
                pb[kb] = f2bf(p);
            }
#pragma unroll
            for (int off = 1; off < 16; off <<= 1) rs += __shfl_xor(rs, off);
            lrun[r] = lrun[r] * sc + rs;
            mrun[r] = mn;
#pragma unroll
            for (int d2 = 0; d2 < 4; ++d2) acc[d2][r] *= sc;
            const int qloc = w * 16 + l4 * 4 + r;
            const unsigned pswz = (qloc & 7) << 4;
#pragma unroll
            for (int kb = 0; kb < 4; ++kb)
                *(unsigned short*)&Psm[qloc * 128 + (((kb * 16 + l15) * 2) ^ pswz)] = pb[kb];
        }

        // O += P V  (k = key; A,B both use key = 8*(l>>4)+i convention)
#pragma unroll
        for (int ks = 0; ks < 2; ++ks) {
            const int qr = w * 16 + l15;
            const unsigned pswz = (qr & 7) << 4;
            bf16x8 pa = *(bf16x8*)&Psm[qr * 128 + ((ks * 64 + l4 * 16) ^ pswz)];
#pragma unroll
            for (int d2 = 0; d2 < 4; ++d2) {
                bf16x8 vb = *(bf16x8*)&Vsm[(d2 * 16 + l15) * 72 + ks * 32 + l4 * 8];
                acc[d2] = __builtin_amdgcn_mfma_f32_16x16x32_bf16(pa, vb, acc[d2], 0, 0, 0);
            }
        }
    }

    // epilogue: normalize; fully-masked rows -> uniform mean over all keys
#pragma unroll
    for (int r = 0; r < 4; ++r) {
        const int qrow = row0 + w * 16 + l4 * 4 + r;
        const float inv = 1.f / lrun[r];
        const bool uni = (mrun[r] <= -1e37f);
#pragma unroll
        for (int d2 = 0; d2 < 4; ++d2) {
            const int d = h * HDd + d2 * 16 + l15;
            const float val = uni ? meanv[b * Dm + d] : acc[d2][r] * inv;
            o[((size_t)(b * Ss + qrow)) * Dm + d] = val;
        }
    }
}

// ---------------------------------------------------------------------------
extern "C" void kernel_launch(void* const* d_in, const int* in_sizes, int n_in,
                              void* d_out, int out_size, void* d_ws, size_t ws_size,
                              hipStream_t stream)
{
    const float* hs     = (const float*)d_in[0];
    const float* amask  = (const float*)d_in[1];
    const float* Wq     = (const float*)d_in[2];
    const float* bq     = (const float*)d_in[3];
    const float* Wk     = (const float*)d_in[4];
    const float* bk     = (const float*)d_in[5];
    const float* dmask  = (const float*)d_in[6];
    const float* Wvq    = (const float*)d_in[7];
    const float* bvq    = (const float*)d_in[8];
    const float* vkeys  = (const float*)d_in[9];
    const float* vembed = (const float*)d_in[10];
    const float* Wo     = (const float*)d_in[11];
    const float* bo     = (const float*)d_in[12];
    float* out = (float*)d_out;

    char* w = (char*)d_ws;
    size_t off = 0;
    auto take = [&](size_t n) { char* p = w + off; off = (off + n + 255) & ~(size_t)255; return p; };
    float* qb    = (float*)take((size_t)Mrows * Dm * 4);
    float* kb    = (float*)take((size_t)Mrows * Dm * 4);
    float* vqb   = (float*)take((size_t)Mrows * DRr * 4);
    float* vbuf  = (float*)take((size_t)Mrows * Dm * 4);
    float* attno = (float*)take((size_t)Mrows * Dm * 4);
    float* pmax  = (float*)take((size_t)Mrows * 8 * 4);
    int*   pidx  = (int*)take((size_t)Mrows * 8 * 4);
    int*   idxb  = (int*)take((size_t)Mrows * 4);
    float* mvb   = (float*)take((size_t)Bb * Dm * 4);

    dim3 blk(256);
    gemm_bias_f32<<<dim3(Dm / 64, Mrows / 64), blk, 0, stream>>>(hs, Wq, bq, qb, Dm, Dm);
    gemm_bias_f32<<<dim3(Dm / 64, Mrows / 64), blk, 0, stream>>>(hs, Wk, bk, kb, Dm, Dm);
    gemm_bias_f32<<<dim3(DRr / 64, Mrows / 64), blk, 0, stream>>>(hs, Wvq, bvq, vqb, DRr, Dm);
    retrieve_argmax_partial<<<dim3(8, Mrows / 64), blk, 0, stream>>>(vqb, vkeys, pmax, pidx);
    argmax_combine<<<dim3((Mrows + 255) / 256), blk, 0, stream>>>(pmax, pidx, idxb);
    build_v<<<dim3(Mrows), blk, 0, stream>>>(hs, vembed, idxb, vbuf);
    mean_v_kernel<<<dim3(Dm / 64, Bb), blk, 0, stream>>>(vbuf, mvb);
    attn_mfma<<<dim3(Ss / 64, Hh, Bb), blk, 0, stream>>>(qb, kb, vbuf, amask, dmask, mvb, attno);
    gemm_bias_f32<<<dim3(Dm / 64, Mrows / 64), blk, 0, stream>>>(attno, Wo, bo, out, Dm, Dm);
}

// Round 3
// 511.726 us; speedup vs baseline: 8.0287x; 1.6280x over previous
//
#include <hip/hip_runtime.h>
#include <math.h>

#define MIN_D (-3.402823466e+38f)

constexpr int Bb = 2, Ss = 2048, Dm = 1024, Hh = 16, HDd = 64, NV = 8192, DRr = 128;
constexpr int Mrows = Bb * Ss;   // 4096

typedef __attribute__((ext_vector_type(8))) short bf16x8;
typedef __attribute__((ext_vector_type(4))) float f32x4;

__device__ inline unsigned short f2bf(float x) {
    union { float f; unsigned u; } v; v.f = x;
    unsigned r = v.u + 0x7fff + ((v.u >> 16) & 1);   // RNE
    return (unsigned short)(r >> 16);
}
__device__ inline float bf2f(unsigned short u) {
    union { unsigned u; float f; } v; v.u = ((unsigned)u) << 16;
    return v.f;
}

// ---------------------------------------------------------------------------
// f32 -> bf16 elementwise (hs conversion). 8 elems/thread.
// ---------------------------------------------------------------------------
__global__ __launch_bounds__(256)
void cvt_bf16(const float* __restrict__ x, unsigned short* __restrict__ y)
{
    size_t i = ((size_t)blockIdx.x * 256 + threadIdx.x) * 8;
    float4 a = *(const float4*)(x + i);
    float4 b = *(const float4*)(x + i + 4);
    uint4 p;
    p.x = (unsigned)f2bf(a.x) | ((unsigned)f2bf(a.y) << 16);
    p.y = (unsigned)f2bf(a.z) | ((unsigned)f2bf(a.w) << 16);
    p.z = (unsigned)f2bf(b.x) | ((unsigned)f2bf(b.y) << 16);
    p.w = (unsigned)f2bf(b.z) | ((unsigned)f2bf(b.w) << 16);
    *(uint4*)(y + i) = p;
}

// ---------------------------------------------------------------------------
// Transpose + convert: W[K][N] f32 -> WT[N][K] bf16. 64x64 tiles.
// ---------------------------------------------------------------------------
__global__ __launch_bounds__(256)
void transpose_cvt(const float* __restrict__ W, unsigned short* __restrict__ WT,
                   int K, int N)
{
    __shared__ unsigned short T[64][72];
    const int tid = threadIdx.x;
    const int n0 = blockIdx.x * 64, k0 = blockIdx.y * 64;
    const int rr = tid >> 4, cc = tid & 15;
#pragma unroll
    for (int q2 = 0; q2 < 4; ++q2) {
        int kk = rr * 4 + q2;
        float4 v = *(const float4*)(W + (size_t)(k0 + kk) * N + n0 + cc * 4);
        T[cc * 4 + 0][kk] = f2bf(v.x);
        T[cc * 4 + 1][kk] = f2bf(v.y);
        T[cc * 4 + 2][kk] = f2bf(v.z);
        T[cc * 4 + 3][kk] = f2bf(v.w);
    }
    __syncthreads();
#pragma unroll
    for (int q2 = 0; q2 < 4; ++q2) {
        int nn = rr * 4 + q2;
        uint2 u;
        u.x = (unsigned)T[nn][cc * 4 + 0] | ((unsigned)T[nn][cc * 4 + 1] << 16);
        u.y = (unsigned)T[nn][cc * 4 + 2] | ((unsigned)T[nn][cc * 4 + 3] << 16);
        *(uint2*)(WT + (size_t)(n0 + nn) * K + k0 + cc * 4) = u;
    }
}

// ---------------------------------------------------------------------------
// bf16 MFMA GEMM: C[M,N] = A[M,K] @ BT[N,K]^T + bias[N]
// BM=128, BN=64, BK=32; 256 thr = 4 waves (2x2), wave tile 64x32.
// [row][32] bf16 tiles (64B rows) -> frag b128 reads naturally conflict-optimal.
// MFMA conventions (R2-verified): A row=l15 k=8*l4+i; B col=l15 k=8*l4+i;
// D row=l4*4+j col=l15.
// ---------------------------------------------------------------------------
template<bool BF16OUT>
__global__ __launch_bounds__(256)
void gemm_bf16(const unsigned short* __restrict__ A,
               const unsigned short* __restrict__ BT,
               const float* __restrict__ bias, void* __restrict__ C,
               int M, int N, int K)
{
    __shared__ __align__(16) unsigned short As[128 * 32];
    __shared__ __align__(16) unsigned short Bs[64 * 32];
    const int tid = threadIdx.x;
    const int l = tid & 63, w = tid >> 6;
    const int l15 = l & 15, l4 = l >> 4;
    const int wm = w >> 1, wn = w & 1;
    const int row0 = blockIdx.y * 128, col0 = blockIdx.x * 64;

    f32x4 acc[4][2];
#pragma unroll
    for (int mi = 0; mi < 4; ++mi)
#pragma unroll
        for (int ni = 0; ni < 2; ++ni) acc[mi][ni] = (f32x4)(0.f);

    for (int k0 = 0; k0 < K; k0 += 32) {
        __syncthreads();
#pragma unroll
        for (int q2 = 0; q2 < 2; ++q2) {   // A tile: 512 16B chunks
            int o = q2 * 256 + tid;
            int r = o >> 2, pc = o & 3;
            uint4 vv = *(const uint4*)(A + (size_t)(row0 + r) * K + k0 + pc * 8);
            *(uint4*)&As[o * 8] = vv;
        }
        {   // B tile: 256 chunks
            int r = tid >> 2, pc = tid & 3;
            uint4 vv = *(const uint4*)(BT + (size_t)(col0 + r) * K + k0 + pc * 8);
            *(uint4*)&Bs[tid * 8] = vv;
        }
        __syncthreads();

        bf16x8 af[4], bf[2];
#pragma unroll
        for (int mi = 0; mi < 4; ++mi)
            af[mi] = *(bf16x8*)&As[(wm * 64 + mi * 16 + l15) * 32 + l4 * 8];
#pragma unroll
        for (int ni = 0; ni < 2; ++ni)
            bf[ni] = *(bf16x8*)&Bs[(wn * 32 + ni * 16 + l15) * 32 + l4 * 8];
#pragma unroll
        for (int mi = 0; mi < 4; ++mi)
#pragma unroll
            for (int ni = 0; ni < 2; ++ni)
                acc[mi][ni] = __builtin_amdgcn_mfma_f32_16x16x32_bf16(af[mi], bf[ni], acc[mi][ni], 0, 0, 0);
    }

#pragma unroll
    for (int mi = 0; mi < 4; ++mi)
#pragma unroll
        for (int ni = 0; ni < 2; ++ni)
#pragma unroll
            for (int j = 0; j < 4; ++j) {
                int row = row0 + wm * 64 + mi * 16 + l4 * 4 + j;
                int col = col0 + wn * 32 + ni * 16 + l15;
                float vv = acc[mi][ni][j] + bias[col];
                if (BF16OUT)
                    ((unsigned short*)C)[(size_t)row * N + col] = f2bf(vv);
                else
                    ((float*)C)[(size_t)row * N + col] = vv;
            }
}

// ---------------------------------------------------------------------------
// f32 GEMM (kept for vq projection; N=128): C = A@W + bias
// ---------------------------------------------------------------------------
__global__ __launch_bounds__(256)
void gemm_bias_f32(const float* __restrict__ A, const float* __restrict__ W,
                   const float* __restrict__ bias, float* __restrict__ C,
                   int N, int K)
{
    __shared__ float As[64][20];
    __shared__ float Ws[16][64];
    const int tid = threadIdx.x;
    const int row0 = blockIdx.y * 64, col0 = blockIdx.x * 64;
    const int tr = tid >> 4, tc = tid & 15;
    float acc[4][4] = {};

    for (int k0 = 0; k0 < K; k0 += 16) {
        {
            int r = tid >> 2, c4 = (tid & 3) << 2;
            float4 av = *(const float4*)(A + (size_t)(row0 + r) * K + k0 + c4);
            *(float4*)&As[r][c4] = av;
        }
        {
            int r = tid >> 4, c4 = (tid & 15) << 2;
            float4 wv = *(const float4*)(W + (size_t)(k0 + r) * N + col0 + c4);
            *(float4*)&Ws[r][c4] = wv;
        }
        __syncthreads();
#pragma unroll
        for (int kk = 0; kk < 16; ++kk) {
            float a[4];
#pragma unroll
            for (int i = 0; i < 4; ++i) a[i] = As[tr * 4 + i][kk];
            float4 bv = *(const float4*)&Ws[kk][tc * 4];
            float b[4] = {bv.x, bv.y, bv.z, bv.w};
#pragma unroll
            for (int i = 0; i < 4; ++i)
#pragma unroll
                for (int j = 0; j < 4; ++j)
                    acc[i][j] = fmaf(a[i], b[j], acc[i][j]);
        }
        __syncthreads();
    }
#pragma unroll
    for (int i = 0; i < 4; ++i) {
        int r = row0 + tr * 4 + i;
        int c = col0 + tc * 4;
        float4 ov;
        ov.x = acc[i][0] + bias[c + 0];
        ov.y = acc[i][1] + bias[c + 1];
        ov.z = acc[i][2] + bias[c + 2];
        ov.w = acc[i][3] + bias[c + 3];
        *(float4*)(C + (size_t)r * N + c) = ov;
    }
}

// ---------------------------------------------------------------------------
// Retrieval (f32 exact — argmax stability). Unchanged from R2 (passing).
// ---------------------------------------------------------------------------
__global__ __launch_bounds__(256)
void retrieve_argmax_partial(const float* __restrict__ vq,
                             const float* __restrict__ vkeys,
                             float* __restrict__ pmax, int* __restrict__ pidx)
{
    __shared__ float Qs[64][132];
    __shared__ float Kt[128][68];
    const int tid = threadIdx.x;
    const int chunk = blockIdx.x;
    const int row0 = blockIdx.y * 64;
    const int tr = tid >> 4, tc = tid & 15;

    {
        int r = tid >> 2, cb = (tid & 3) * 32;
#pragma unroll
        for (int l = 0; l < 8; ++l) {
            float4 v = *(const float4*)(vq + (size_t)(row0 + r) * DRr + cb + l * 4);
            *(float4*)&Qs[r][cb + l * 4] = v;
        }
    }

    float vmax[4];
    int   vidx[4];
#pragma unroll
    for (int i = 0; i < 4; ++i) { vmax[i] = -INFINITY; vidx[i] = 0; }

    for (int nt = 0; nt < 16; ++nt) {
        const int n0 = chunk * 1024 + nt * 64;
        __syncthreads();
        {
            int n = tid >> 2, kb = (tid & 3) * 32;
#pragma unroll
            for (int l = 0; l < 8; ++l) {
                float4 v = *(const float4*)(vkeys + (size_t)(n0 + n) * DRr + kb + l * 4);
                Kt[kb + l * 4 + 0][n] = v.x;
                Kt[kb + l * 4 + 1][n] = v.y;
                Kt[kb + l * 4 + 2][n] = v.z;
                Kt[kb + l * 4 + 3][n] = v.w;
            }
        }
        __syncthreads();

        float acc[4][4] = {};
#pragma unroll 8
        for (int kk = 0; kk < 128; ++kk) {
            float a[4];
#pragma unroll
            for (int i = 0; i < 4; ++i) a[i] = Qs[tr * 4 + i][kk];
            float4 bv = *(const float4*)&Kt[kk][tc * 4];
            float b[4] = {bv.x, bv.y, bv.z, bv.w};
#pragma unroll
            for (int i = 0; i < 4; ++i)
#pragma unroll
                for (int j = 0; j < 4; ++j)
                    acc[i][j] = fmaf(a[i], b[j], acc[i][j]);
        }
#pragma unroll
        for (int i = 0; i < 4; ++i)
#pragma unroll
            for (int j = 0; j < 4; ++j) {
                int n = n0 + tc * 4 + j;
                if (acc[i][j] > vmax[i]) { vmax[i] = acc[i][j]; vidx[i] = n; }
            }
    }

#pragma unroll
    for (int off = 1; off < 16; off <<= 1) {
#pragma unroll
        for (int i = 0; i < 4; ++i) {
            float om = __shfl_xor(vmax[i], off);
            int   oi = __shfl_xor(vidx[i], off);
            if (om > vmax[i] || (om == vmax[i] && oi < vidx[i])) { vmax[i] = om; vidx[i] = oi; }
        }
    }
    if (tc == 0) {
#pragma unroll
        for (int i = 0; i < 4; ++i) {
            int r = row0 + tr * 4 + i;
            pmax[r * 8 + chunk] = vmax[i];
            pidx[r * 8 + chunk] = vidx[i];
        }
    }
}

__global__ void argmax_combine(const float* __restrict__ pmax,
                               const int* __restrict__ pidx,
                               int* __restrict__ idx)
{
    int r = blockIdx.x * blockDim.x + threadIdx.x;
    if (r >= Mrows) return;
    float best = pmax[r * 8];
    int   bi   = pidx[r * 8];
#pragma unroll
    for (int c = 1; c < 8; ++c) {
        float m2 = pmax[r * 8 + c];
        int   i2 = pidx[r * 8 + c];
        if (m2 > best || (m2 == best && i2 < bi)) { best = m2; bi = i2; }
    }
    idx[r] = bi;
}

// ---------------------------------------------------------------------------
// v = hs * v_embed[idx], written as bf16.
// ---------------------------------------------------------------------------
__global__ __launch_bounds__(256)
void build_v_bf16(const float* __restrict__ hs, const float* __restrict__ vembed,
                  const int* __restrict__ idx, unsigned short* __restrict__ v)
{
    int row = blockIdx.x;
    int id = idx[row];
    int c = threadIdx.x * 4;
    float4 a = *(const float4*)(hs + (size_t)row * Dm + c);
    float4 e = *(const float4*)(vembed + (size_t)id * Dm + c);
    uint2 u;
    u.x = (unsigned)f2bf(a.x * e.x) | ((unsigned)f2bf(a.y * e.y) << 16);
    u.y = (unsigned)f2bf(a.z * e.z) | ((unsigned)f2bf(a.w * e.w) << 16);
    *(uint2*)(v + (size_t)row * Dm + c) = u;
}

// ---------------------------------------------------------------------------
// meanv[b][d] = mean over s of v (bf16 in, f32 out) — for fully-masked rows.
// ---------------------------------------------------------------------------
__global__ __launch_bounds__(256)
void mean_v_kernel(const unsigned short* __restrict__ v, float* __restrict__ mv)
{
    __shared__ float part[4][64];
    const int d0 = blockIdx.x * 64;
    const int b  = blockIdx.y;
    const int dl = threadIdx.x & 63, jc = threadIdx.x >> 6;
    float s = 0.f;
#pragma unroll 4
    for (int j = jc * 512; j < jc * 512 + 512; ++j)
        s += bf2f(v[((size_t)(b * Ss + j)) * Dm + d0 + dl]);
    part[jc][dl] = s;
    __syncthreads();
    if (threadIdx.x < 64) {
        float t = part[0][dl] + part[1][dl] + part[2][dl] + part[3][dl];
        mv[b * Dm + d0 + dl] = t * (1.f / 2048.f);
    }
}

// ---------------------------------------------------------------------------
// bf16 MFMA flash attention, v2: all-bf16 inputs, conflict-optimal LDS.
// K tile [64key][64d] staged with chunk-XOR swizzle (pc = c ^ (key&7)).
// V tile staged TRANSPOSED [64d][64key] via coalesced reads (thread=d col,
// wave=key octet) + b128 XOR-swizzled writes. Mask as 2048-bit LDS bitmask.
// Causal tile skip; fully-masked rows -> meanv (uniform softmax semantics).
// ---------------------------------------------------------------------------
__global__ __launch_bounds__(256)
void attn_mfma2(const unsigned short* __restrict__ q, const unsigned short* __restrict__ k,
                const unsigned short* __restrict__ v, const float* __restrict__ am,
                const float* __restrict__ dm, const float* __restrict__ meanv,
                unsigned short* __restrict__ o)
{
    __shared__ __align__(16) unsigned char Ksm[64 * 128];
    __shared__ __align__(16) unsigned char Vsm[64 * 128];   // [d][key] bf16, swizzled
    __shared__ __align__(16) unsigned char Psm[64 * 128];
    __shared__ unsigned char mb[256];

    const int tid = threadIdx.x;
    const int l = tid & 63, w = tid >> 6;
    const int l15 = l & 15, l4 = l >> 4;
    const int qt = gridDim.x - 1 - blockIdx.x;   // heavy tiles first
    const int h = blockIdx.y, b = blockIdx.z;
    const int row0 = qt * 64;

    {   // 2048-bit mask: bit=1 means masked (am*dm == 0)
        unsigned byte = 0;
#pragma unroll
        for (int j = 0; j < 8; ++j) {
            int c = tid * 8 + j;
            byte |= (unsigned)((am[b * Ss + c] * dm[h * Ss + c]) == 0.f) << j;
        }
        mb[tid] = (unsigned char)byte;
    }

    // Q fragments direct from global bf16 (row = l15 of this wave's 16 q rows)
    bf16x8 qf[2];
    {
        const unsigned short* qp = q + ((size_t)(b * Ss + row0 + w * 16 + l15)) * Dm
                                   + h * HDd + l4 * 8;
        qf[0] = *(const bf16x8*)qp;
        qf[1] = *(const bf16x8*)(qp + 32);
    }

    f32x4 acc[4];
#pragma unroll
    for (int d2 = 0; d2 < 4; ++d2) acc[d2] = (f32x4)(0.f);
    float mrun[4], lrun[4];
#pragma unroll
    for (int r = 0; r < 4; ++r) { mrun[r] = -INFINITY; lrun[r] = 0.f; }

    for (int kt = 0; kt <= qt; ++kt) {
        __syncthreads();   // prev tile consumed (also covers mb on kt=0)
        {   // K stage: 512 chunks of 16B, source chunk-swizzled, LDS linear
#pragma unroll
            for (int q2 = 0; q2 < 2; ++q2) {
                int ochunk = q2 * 256 + tid;
                int key = ochunk >> 3, pc = ochunk & 7;
                int lc = pc ^ (key & 7);
                uint4 vv = *(const uint4*)(k + ((size_t)(b * Ss + kt * 64 + key)) * Dm
                                           + h * HDd + lc * 8);
                *(uint4*)&Ksm[ochunk * 16] = vv;
            }
        }
        {   // V stage transposed: thread=(d=l, keygrp=w), coalesced 128B row reads
            const unsigned short* vp = v + ((size_t)(b * Ss + kt * 64 + w * 16)) * Dm
                                       + h * HDd + l;
            unsigned vr[8];
#pragma unroll
            for (int j2 = 0; j2 < 8; ++j2) {
                unsigned lo = vp[(size_t)(2 * j2) * Dm];
                unsigned hi = vp[(size_t)(2 * j2 + 1) * Dm];
                vr[j2] = lo | (hi << 16);
            }
            const unsigned swz = (l & 7) << 4;
            uint4 a0; a0.x = vr[0]; a0.y = vr[1]; a0.z = vr[2]; a0.w = vr[3];
            uint4 a1; a1.x = vr[4]; a1.y = vr[5]; a1.z = vr[6]; a1.w = vr[7];
            *(uint4*)&Vsm[l * 128 + ((w * 32) ^ swz)]      = a0;
            *(uint4*)&Vsm[l * 128 + ((w * 32 + 16) ^ swz)] = a1;
        }
        __syncthreads();

        // S = Q K^T
        f32x4 sreg[4];
#pragma unroll
        for (int kb = 0; kb < 4; ++kb) {
            const int key = kb * 16 + l15;
            const int sw = key & 7;
            bf16x8 k0 = *(bf16x8*)&Ksm[key * 128 + ((l4 ^ sw) * 16)];
            bf16x8 k1 = *(bf16x8*)&Ksm[key * 128 + (((4 + l4) ^ sw) * 16)];
            f32x4 s = (f32x4)(0.f);
            s = __builtin_amdgcn_mfma_f32_16x16x32_bf16(qf[0], k0, s, 0, 0, 0);
            s = __builtin_amdgcn_mfma_f32_16x16x32_bf16(qf[1], k1, s, 0, 0, 0);
            sreg[kb] = s;
        }

        // mask + online softmax + P store (bf16, swizzled, wave-private rows)
#pragma unroll
        for (int r = 0; r < 4; ++r) {
            const int qrow = row0 + w * 16 + l4 * 4 + r;
            float sv[4];
#pragma unroll
            for (int kb = 0; kb < 4; ++kb) {
                const int col = kt * 64 + kb * 16 + l15;
                const bool masked = (col > qrow) || ((mb[col >> 3] >> (col & 7)) & 1);
                sv[kb] = sreg[kb][r] * 0.125f + (masked ? MIN_D : 0.f);
            }
            float pm = fmaxf(fmaxf(sv[0], sv[1]), fmaxf(sv[2], sv[3]));
#pragma unroll
            for (int off = 1; off < 16; off <<= 1) pm = fmaxf(pm, __shfl_xor(pm, off));
            const float mn = fmaxf(mrun[r], pm);
            const float sc = __expf(mrun[r] - mn);
            float rs = 0.f;
            unsigned short pb[4];
#pragma unroll
            for (int kb = 0; kb < 4; ++kb) {
                float p = __expf(sv[kb] - mn);
                rs += p;
                pb[kb] = f2bf(p);
            }
#pragma unroll
            for (int off = 1; off < 16; off <<= 1) rs += __shfl_xor(rs, off);
            lrun[r] = lrun[r] * sc + rs;
            mrun[r] = mn;
#pragma unroll
            for (int d2 = 0; d2 < 4; ++d2) acc[d2][r] *= sc;
            const int qloc = w * 16 + l4 * 4 + r;
            const unsigned pswz = (qloc & 7) << 4;
#pragma unroll
            for (int kb = 0; kb < 4; ++kb)
                *(unsigned short*)&Psm[qloc * 128 + (((kb * 16 + l15) * 2) ^ pswz)] = pb[kb];
        }

        // O += P V
#pragma unroll
        for (int ks = 0; ks < 2; ++ks) {
            const int qr = w * 16 + l15;
            const unsigned pswz = (qr & 7) << 4;
            bf16x8 pa = *(bf16x8*)&Psm[qr * 128 + ((ks * 64 + l4 * 16) ^ pswz)];
#pragma unroll
            for (int d2 = 0; d2 < 4; ++d2) {
                const int dd = d2 * 16 + l15;
                bf16x8 vb = *(bf16x8*)&Vsm[dd * 128 + ((ks * 64 + l4 * 16) ^ ((dd & 7) << 4))];
                acc[d2] = __builtin_amdgcn_mfma_f32_16x16x32_bf16(pa, vb, acc[d2], 0, 0, 0);
            }
        }
    }

    // epilogue: normalize -> bf16; fully-masked rows -> uniform mean over all keys
#pragma unroll
    for (int r = 0; r < 4; ++r) {
        const int qrow = row0 + w * 16 + l4 * 4 + r;
        const float inv = 1.f / lrun[r];
        const bool uni = (mrun[r] <= -1e37f);
#pragma unroll
        for (int d2 = 0; d2 < 4; ++d2) {
            const int d = h * HDd + d2 * 16 + l15;
            const float val = uni ? meanv[b * Dm + d] : acc[d2][r] * inv;
            o[((size_t)(b * Ss + qrow)) * Dm + d] = f2bf(val);
        }
    }
}

// ---------------------------------------------------------------------------
extern "C" void kernel_launch(void* const* d_in, const int* in_sizes, int n_in,
                              void* d_out, int out_size, void* d_ws, size_t ws_size,
                              hipStream_t stream)
{
    const float* hs     = (const float*)d_in[0];
    const float* amask  = (const float*)d_in[1];
    const float* Wq     = (const float*)d_in[2];
    const float* bq     = (const float*)d_in[3];
    const float* Wk     = (const float*)d_in[4];
    const float* bk     = (const float*)d_in[5];
    const float* dmask  = (const float*)d_in[6];
    const float* Wvq    = (const float*)d_in[7];
    const float* bvq    = (const float*)d_in[8];
    const float* vkeys  = (const float*)d_in[9];
    const float* vembed = (const float*)d_in[10];
    const float* Wo     = (const float*)d_in[11];
    const float* bo     = (const float*)d_in[12];
    float* out = (float*)d_out;

    char* w = (char*)d_ws;
    size_t off = 0;
    auto take = [&](size_t n) { char* p = w + off; off = (off + n + 255) & ~(size_t)255; return p; };
    unsigned short* hsbf  = (unsigned short*)take((size_t)Mrows * Dm * 2);
    unsigned short* WqT   = (unsigned short*)take((size_t)Dm * Dm * 2);
    unsigned short* WkT   = (unsigned short*)take((size_t)Dm * Dm * 2);
    unsigned short* WoT   = (unsigned short*)take((size_t)Dm * Dm * 2);
    unsigned short* qbf   = (unsigned short*)take((size_t)Mrows * Dm * 2);
    unsigned short* kbf   = (unsigned short*)take((size_t)Mrows * Dm * 2);
    unsigned short* vbuf  = (unsigned short*)take((size_t)Mrows * Dm * 2);
    unsigned short* attno = (unsigned short*)take((size_t)Mrows * Dm * 2);
    float* vqb   = (float*)take((size_t)Mrows * DRr * 4);
    float* pmax  = (float*)take((size_t)Mrows * 8 * 4);
    int*   pidx  = (int*)take((size_t)Mrows * 8 * 4);
    int*   idxb  = (int*)take((size_t)Mrows * 4);
    float* mvb   = (float*)take((size_t)Bb * Dm * 4);

    dim3 blk(256);
    // dtype prep
    cvt_bf16<<<dim3(Mrows * Dm / 2048), blk, 0, stream>>>(hs, hsbf);
    transpose_cvt<<<dim3(Dm / 64, Dm / 64), blk, 0, stream>>>(Wq, WqT, Dm, Dm);
    transpose_cvt<<<dim3(Dm / 64, Dm / 64), blk, 0, stream>>>(Wk, WkT, Dm, Dm);
    transpose_cvt<<<dim3(Dm / 64, Dm / 64), blk, 0, stream>>>(Wo, WoT, Dm, Dm);
    // projections (bf16 MFMA)
    gemm_bf16<true><<<dim3(Dm / 64, Mrows / 128), blk, 0, stream>>>(hsbf, WqT, bq, qbf, Mrows, Dm, Dm);
    gemm_bf16<true><<<dim3(Dm / 64, Mrows / 128), blk, 0, stream>>>(hsbf, WkT, bk, kbf, Mrows, Dm, Dm);
    // retrieval chain (exact f32)
    gemm_bias_f32<<<dim3(DRr / 64, Mrows / 64), blk, 0, stream>>>(hs, Wvq, bvq, vqb, DRr, Dm);
    retrieve_argmax_partial<<<dim3(8, Mrows / 64), blk, 0, stream>>>(vqb, vkeys, pmax, pidx);
    argmax_combine<<<dim3((Mrows + 255) / 256), blk, 0, stream>>>(pmax, pidx, idxb);
    build_v_bf16<<<dim3(Mrows), blk, 0, stream>>>(hs, vembed, idxb, vbuf);
    mean_v_kernel<<<dim3(Dm / 64, Bb), blk, 0, stream>>>(vbuf, mvb);
    // attention
    attn_mfma2<<<dim3(Ss / 64, Hh, Bb), blk, 0, stream>>>(qbf, kbf, vbuf, amask, dmask, mvb, attno);
    // output projection (f32 out)
    gemm_bf16<false><<<dim3(Dm / 64, Mrows / 128), blk, 0, stream>>>(attno, WoT, bo, out, Mrows, Dm, Dm);
}